// Round 1
// baseline (681.222 us; speedup 1.0000x reference)
//
#include <hip/hip_runtime.h>
#include <math.h>

#define N_VOX 32768
#define N_EMB 8192
#define DIM 64
#define NCHUNK 8
#define CHUNK (N_EMB / NCHUNK)   // 1024 codes per chunk

// -------- kernel A: codebook squared norms --------
__global__ __launch_bounds__(256) void esq_kernel(const float* __restrict__ cb,
                                                  float* __restrict__ esq) {
    int gid  = blockIdx.x * blockDim.x + threadIdx.x;
    int code = gid >> 6;          // one wave (64 lanes) per code
    int lane = threadIdx.x & 63;
    float v = cb[(size_t)code * DIM + lane];
    float s = v * v;
    #pragma unroll
    for (int off = 32; off > 0; off >>= 1)
        s += __shfl_down(s, off, 64);
    if (lane == 0) esq[code] = s;
}

// -------- kernel B: per-(row, chunk) argmin scan --------
// score = ||e||^2 - 2*z.e  (z_sq is a per-row constant; irrelevant for argmin)
__global__ __launch_bounds__(256) void scan_kernel(const float* __restrict__ z,
                                                   const float* __restrict__ cb,
                                                   const float* __restrict__ esq,
                                                   float* __restrict__ cand_val,
                                                   int* __restrict__ cand_idx) {
    int row   = blockIdx.x * blockDim.x + threadIdx.x;
    int chunk = blockIdx.y;            // wave-uniform -> codebook addr uniform
    int k0    = chunk * CHUNK;

    // z row -> registers (16 x float4)
    float zr[DIM];
    const float4* zp = (const float4*)(z + (size_t)row * DIM);
    #pragma unroll
    for (int d = 0; d < DIM / 4; ++d) {
        float4 t = zp[d];
        zr[4*d+0] = t.x; zr[4*d+1] = t.y; zr[4*d+2] = t.z; zr[4*d+3] = t.w;
    }

    float best = 3.4e38f;
    int   bidx = k0;
    const float* ep = cb + (size_t)k0 * DIM;
    for (int k = 0; k < CHUNK; ++k) {
        float a0 = 0.f, a1 = 0.f, a2 = 0.f, a3 = 0.f;
        #pragma unroll
        for (int d = 0; d < DIM; d += 4) {
            a0 = fmaf(ep[d+0], zr[d+0], a0);
            a1 = fmaf(ep[d+1], zr[d+1], a1);
            a2 = fmaf(ep[d+2], zr[d+2], a2);
            a3 = fmaf(ep[d+3], zr[d+3], a3);
        }
        float dot   = (a0 + a1) + (a2 + a3);
        float score = esq[k0 + k] - 2.0f * dot;
        if (score < best) { best = score; bidx = k0 + k; }   // strict < => first occurrence
        ep += DIM;
    }
    cand_val[(size_t)chunk * N_VOX + row] = best;
    cand_idx[(size_t)chunk * N_VOX + row] = bidx;
}

// -------- kernel C: final argmin, gather, quantized + index + loss partials --------
__global__ __launch_bounds__(256) void finalize_kernel(const float* __restrict__ z,
                                                       const float* __restrict__ cb,
                                                       const float* __restrict__ cand_val,
                                                       const int* __restrict__ cand_idx,
                                                       float* __restrict__ out,
                                                       float* __restrict__ partials) {
    int row = blockIdx.x * 256 + threadIdx.x;

    float best = 3.4e38f;
    int   bidx = 0;
    #pragma unroll
    for (int c = 0; c < NCHUNK; ++c) {       // ascending chunk order: ties keep lowest index
        float v  = cand_val[(size_t)c * N_VOX + row];
        int   id = cand_idx[(size_t)c * N_VOX + row];
        if (v < best) { best = v; bidx = id; }
    }

    out[(size_t)N_VOX * DIM + 2 + row] = (float)bidx;   // indices as fp32

    const float4* qp = (const float4*)(cb + (size_t)bidx * DIM);
    const float4* zp = (const float4*)(z  + (size_t)row  * DIM);
    float4*       op = (float4*)(out + (size_t)row * DIM);

    float ss = 0.f;
    #pragma unroll
    for (int d = 0; d < DIM / 4; ++d) {
        float4 zt = zp[d], qt = qp[d];
        float dx = qt.x - zt.x, dy = qt.y - zt.y;
        float dz = qt.z - zt.z, dw = qt.w - zt.w;
        float4 o;
        o.x = zt.x + dx; o.y = zt.y + dy;   // mirrors reference's z + (q - z)
        o.z = zt.z + dz; o.w = zt.w + dw;
        op[d] = o;
        ss += dx*dx + dy*dy + dz*dz + dw*dw;
    }

    __shared__ float red[256];
    red[threadIdx.x] = ss;
    __syncthreads();
    #pragma unroll
    for (int s = 128; s > 0; s >>= 1) {
        if (threadIdx.x < s) red[threadIdx.x] += red[threadIdx.x + s];
        __syncthreads();
    }
    if (threadIdx.x == 0) partials[blockIdx.x] = red[0];
}

// -------- kernel D: reduce partials -> both losses --------
__global__ __launch_bounds__(128) void loss_kernel(const float* __restrict__ partials,
                                                   float* __restrict__ out) {
    __shared__ float red[128];
    red[threadIdx.x] = partials[threadIdx.x];
    __syncthreads();
    #pragma unroll
    for (int s = 64; s > 0; s >>= 1) {
        if (threadIdx.x < s) red[threadIdx.x] += red[threadIdx.x + s];
        __syncthreads();
    }
    if (threadIdx.x == 0) {
        float mean = red[0] / (float)((size_t)N_VOX * DIM);
        out[(size_t)N_VOX * DIM + 0] = mean;   // vq_loss
        out[(size_t)N_VOX * DIM + 1] = mean;   // commitment_loss (identical forward value)
    }
}

extern "C" void kernel_launch(void* const* d_in, const int* in_sizes, int n_in,
                              void* d_out, int out_size, void* d_ws, size_t ws_size,
                              hipStream_t stream) {
    const float* z  = (const float*)d_in[0];   // [32768, 64]
    const float* cb = (const float*)d_in[1];   // [8192, 64]
    float* out = (float*)d_out;

    // ws layout: esq [8192] | cand_val [8*32768] | cand_idx [8*32768] | partials [128]
    float* esq      = (float*)d_ws;
    float* cand_val = esq + N_EMB;
    int*   cand_idx = (int*)(cand_val + (size_t)N_VOX * NCHUNK);
    float* partials = (float*)(cand_idx + (size_t)N_VOX * NCHUNK);

    esq_kernel<<<dim3(N_EMB * 64 / 256), dim3(256), 0, stream>>>(cb, esq);
    scan_kernel<<<dim3(N_VOX / 256, NCHUNK), dim3(256), 0, stream>>>(z, cb, esq, cand_val, cand_idx);
    finalize_kernel<<<dim3(N_VOX / 256), dim3(256), 0, stream>>>(z, cb, cand_val, cand_idx, out, partials);
    loss_kernel<<<1, 128, 0, stream>>>(partials, out);
}

// Round 2
// 211.286 us; speedup vs baseline: 3.2242x; 3.2242x over previous
//
#include <hip/hip_runtime.h>
#include <math.h>

#define N_VOX 32768
#define N_EMB 8192
#define DIM 64
#define NCHUNK 8
#define CODES_PER_CHUNK (N_EMB / NCHUNK)        // 1024
#define TILES_PER_CHUNK (CODES_PER_CHUNK / 16)  // 64
#define NTILE_TOT (N_EMB / 16)                  // 512

typedef _Float16 half8 __attribute__((ext_vector_type(8)));
typedef float floatx4 __attribute__((ext_vector_type(4)));

#define FP16_MIN_NORMAL 6.1035156e-5f
#define LO_SCALE 2048.0f
#define INV_LO_SCALE (1.0f / 2048.0f)

// Split fp32 -> f16 hi + scaled f16 lo. hi forced to 0 if subnormal so lo
// captures it exactly (sidesteps any MFMA input-denorm flush ambiguity).
__device__ inline void split8(const float* __restrict__ p, half8& h, half8& l) {
    #pragma unroll
    for (int j = 0; j < 8; ++j) {
        float x  = p[j];
        _Float16 hi = (_Float16)x;
        float hf = (float)hi;
        if (fabsf(hf) < FP16_MIN_NORMAL) { hi = (_Float16)0.f; hf = 0.f; }
        h[j] = hi;
        l[j] = (_Float16)((x - hf) * LO_SCALE);
    }
}

// -------- kernel A: codebook squared norms (unchanged, validated R1) --------
__global__ __launch_bounds__(256) void esq_kernel(const float* __restrict__ cb,
                                                  float* __restrict__ esq) {
    int gid  = blockIdx.x * blockDim.x + threadIdx.x;
    int code = gid >> 6;
    int lane = threadIdx.x & 63;
    float v = cb[(size_t)code * DIM + lane];
    float s = v * v;
    #pragma unroll
    for (int off = 32; off > 0; off >>= 1)
        s += __shfl_down(s, off, 64);
    if (lane == 0) esq[code] = s;
}

// -------- kernel B: codebook -> MFMA B-fragment-ordered f16 hi/lo --------
// Fragment mapping for mfma_f32_16x16x32: lane l holds elem[n = l&15][k = (l>>4)*8 + j].
// Stored per (tile nt, K-chunk c): frag index fi = nt*2 + c, addr (fi*64 + l)*8 halves.
__global__ __launch_bounds__(256) void cbprep_kernel(const float* __restrict__ cb,
                                                     _Float16* __restrict__ eh,
                                                     _Float16* __restrict__ el) {
    int t  = blockIdx.x * 256 + threadIdx.x;   // 65536 threads
    int l  = t & 63;
    int fi = t >> 6;                           // 0..1023 = nt*2 + c
    int nt = fi >> 1;
    int c  = fi & 1;
    int code = nt * 16 + (l & 15);
    int k0   = c * 32 + (l >> 4) * 8;
    half8 h, lo;
    split8(cb + (size_t)code * DIM + k0, h, lo);
    ((half8*)eh)[(size_t)fi * 64 + l] = h;
    ((half8*)el)[(size_t)fi * 64 + l] = lo;
}

// -------- kernel C: MFMA argmin scan --------
// Block = 4 waves, all on the same code chunk (shared B stream -> L1 reuse).
// Wave owns 64 rows (4 row-tiles of 16) x 1024 codes (64 tiles of 16).
__global__ __launch_bounds__(256) void scan_kernel(const float* __restrict__ z,
                                                   const _Float16* __restrict__ eh,
                                                   const _Float16* __restrict__ el,
                                                   const float* __restrict__ esq,
                                                   int* __restrict__ cand_idx) {
    int tid   = threadIdx.x;
    int l     = tid & 63;
    int w     = tid >> 6;                    // wave in block: 0..3
    int chunk = blockIdx.x & 7;
    int rg    = (blockIdx.x >> 3) * 4 + w;   // row group 0..511 (64 rows each)
    int col   = l & 15;
    int quad  = l >> 4;

    // A-fragments: z rows split on the fly. zh[rt][c], zl[rt][c].
    half8 zh[4][2], zl[4][2];
    #pragma unroll
    for (int rt = 0; rt < 4; ++rt) {
        int row = rg * 64 + rt * 16 + col;
        const float* zp = z + (size_t)row * DIM + quad * 8;
        split8(zp,      zh[rt][0], zl[rt][0]);
        split8(zp + 32, zh[rt][1], zl[rt][1]);
    }

    const half8* ehf = (const half8*)eh;
    const half8* elf = (const half8*)el;
    int ntBase = chunk * TILES_PER_CHUNK;

    // Prefetch tile 0 B-fragments
    half8 bh0 = ehf[(size_t)(ntBase * 2 + 0) * 64 + l];
    half8 bh1 = ehf[(size_t)(ntBase * 2 + 1) * 64 + l];
    half8 bl0 = elf[(size_t)(ntBase * 2 + 0) * 64 + l];
    half8 bl1 = elf[(size_t)(ntBase * 2 + 1) * 64 + l];

    float minv[4][4];
    int   mini[4][4];
    #pragma unroll
    for (int rt = 0; rt < 4; ++rt)
        #pragma unroll
        for (int i = 0; i < 4; ++i) { minv[rt][i] = 3.4e38f; mini[rt][i] = 0; }

    for (int t = 0; t < TILES_PER_CHUNK; ++t) {
        int nt = ntBase + t;
        half8 ch0 = bh0, ch1 = bh1, cl0 = bl0, cl1 = bl1;
        if (t < TILES_PER_CHUNK - 1) {
            int nn = nt + 1;
            bh0 = ehf[(size_t)(nn * 2 + 0) * 64 + l];
            bh1 = ehf[(size_t)(nn * 2 + 1) * 64 + l];
            bl0 = elf[(size_t)(nn * 2 + 0) * 64 + l];
            bl1 = elf[(size_t)(nn * 2 + 1) * 64 + l];
        }
        float esqv = esq[nt * 16 + col];

        #pragma unroll
        for (int rt = 0; rt < 4; ++rt) {
            floatx4 hh = {0.f, 0.f, 0.f, 0.f};
            floatx4 cc = {0.f, 0.f, 0.f, 0.f};
            cc = __builtin_amdgcn_mfma_f32_16x16x32_f16(zl[rt][0], ch0, cc, 0, 0, 0);
            cc = __builtin_amdgcn_mfma_f32_16x16x32_f16(zh[rt][0], cl0, cc, 0, 0, 0);
            hh = __builtin_amdgcn_mfma_f32_16x16x32_f16(zh[rt][0], ch0, hh, 0, 0, 0);
            cc = __builtin_amdgcn_mfma_f32_16x16x32_f16(zl[rt][1], ch1, cc, 0, 0, 0);
            cc = __builtin_amdgcn_mfma_f32_16x16x32_f16(zh[rt][1], cl1, cc, 0, 0, 0);
            hh = __builtin_amdgcn_mfma_f32_16x16x32_f16(zh[rt][1], ch1, hh, 0, 0, 0);

            int codei = nt * 16 + col;
            #pragma unroll
            for (int i = 0; i < 4; ++i) {
                // score = esq - 2*(hh + cc/2048)
                float s = fmaf(-2.0f, hh[i], fmaf(-2.0f * INV_LO_SCALE, cc[i], esqv));
                if (s < minv[rt][i]) { minv[rt][i] = s; mini[rt][i] = codei; }
            }
        }
    }

    // Cross-lane argmin: C-layout row = quad*4+i lives in the 16 lanes of this
    // quad (col = l&15). Butterfly over lane bits 0..3, tie -> lower index.
    #pragma unroll
    for (int rt = 0; rt < 4; ++rt) {
        #pragma unroll
        for (int i = 0; i < 4; ++i) {
            float v  = minv[rt][i];
            int   id = mini[rt][i];
            #pragma unroll
            for (int off = 1; off < 16; off <<= 1) {
                float ov = __shfl_xor(v, off, 16);
                int   oi = __shfl_xor(id, off, 16);
                if (ov < v || (ov == v && oi < id)) { v = ov; id = oi; }
            }
            if (col == 0) {
                int row = rg * 64 + rt * 16 + quad * 4 + i;
                cand_idx[chunk * N_VOX + row] = id;
            }
        }
    }
}

// -------- kernel D: fp32 re-score of the 8 chunk winners (exact R1 math), --------
// -------- gather, quantized + index + loss partials --------
__global__ __launch_bounds__(256) void finalize_kernel(const float* __restrict__ z,
                                                       const float* __restrict__ cb,
                                                       const float* __restrict__ esq,
                                                       const int* __restrict__ cand_idx,
                                                       float* __restrict__ out,
                                                       float* __restrict__ partials) {
    int row = blockIdx.x * 256 + threadIdx.x;

    // z row -> registers
    float zr[DIM];
    const float4* zp4 = (const float4*)(z + (size_t)row * DIM);
    #pragma unroll
    for (int d = 0; d < DIM / 4; ++d) {
        float4 t = zp4[d];
        zr[4*d+0] = t.x; zr[4*d+1] = t.y; zr[4*d+2] = t.z; zr[4*d+3] = t.w;
    }

    float best = 3.4e38f;
    int   bidx = 0;
    #pragma unroll
    for (int c = 0; c < NCHUNK; ++c) {   // candidate ids ascend with c
        int id = cand_idx[c * N_VOX + row];
        const float* ep = cb + (size_t)id * DIM;
        float a0 = 0.f, a1 = 0.f, a2 = 0.f, a3 = 0.f;
        #pragma unroll
        for (int d = 0; d < DIM; d += 4) {   // identical 4-chain to validated R1
            a0 = fmaf(ep[d+0], zr[d+0], a0);
            a1 = fmaf(ep[d+1], zr[d+1], a1);
            a2 = fmaf(ep[d+2], zr[d+2], a2);
            a3 = fmaf(ep[d+3], zr[d+3], a3);
        }
        float dot   = (a0 + a1) + (a2 + a3);
        float score = esq[id] - 2.0f * dot;
        if (score < best) { best = score; bidx = id; }
    }

    out[(size_t)N_VOX * DIM + 2 + row] = (float)bidx;   // indices as fp32

    const float4* qp = (const float4*)(cb + (size_t)bidx * DIM);
    float4*       op = (float4*)(out + (size_t)row * DIM);

    float ss = 0.f;
    #pragma unroll
    for (int d = 0; d < DIM / 4; ++d) {
        float4 qt = qp[d];
        float zx = zr[4*d+0], zy = zr[4*d+1], zz = zr[4*d+2], zw = zr[4*d+3];
        float dx = qt.x - zx, dy = qt.y - zy, dz = qt.z - zz, dw = qt.w - zw;
        float4 o;
        o.x = zx + dx; o.y = zy + dy; o.z = zz + dz; o.w = zw + dw;
        op[d] = o;
        ss += dx*dx + dy*dy + dz*dz + dw*dw;
    }

    __shared__ float red[256];
    red[threadIdx.x] = ss;
    __syncthreads();
    #pragma unroll
    for (int s = 128; s > 0; s >>= 1) {
        if (threadIdx.x < s) red[threadIdx.x] += red[threadIdx.x + s];
        __syncthreads();
    }
    if (threadIdx.x == 0) partials[blockIdx.x] = red[0];
}

// -------- kernel E: reduce partials -> both losses --------
__global__ __launch_bounds__(128) void loss_kernel(const float* __restrict__ partials,
                                                   float* __restrict__ out) {
    __shared__ float red[128];
    red[threadIdx.x] = partials[threadIdx.x];
    __syncthreads();
    #pragma unroll
    for (int s = 64; s > 0; s >>= 1) {
        if (threadIdx.x < s) red[threadIdx.x] += red[threadIdx.x + s];
        __syncthreads();
    }
    if (threadIdx.x == 0) {
        float mean = red[0] / (float)((size_t)N_VOX * DIM);
        out[(size_t)N_VOX * DIM + 0] = mean;   // vq_loss
        out[(size_t)N_VOX * DIM + 1] = mean;   // commitment_loss
    }
}

extern "C" void kernel_launch(void* const* d_in, const int* in_sizes, int n_in,
                              void* d_out, int out_size, void* d_ws, size_t ws_size,
                              hipStream_t stream) {
    const float* z  = (const float*)d_in[0];   // [32768, 64]
    const float* cb = (const float*)d_in[1];   // [8192, 64]
    float* out = (float*)d_out;

    // ws: eh [512K halves =1MB] | el [1MB] | esq [32KB] | cand_idx [1MB] | partials
    _Float16* eh      = (_Float16*)d_ws;
    _Float16* el      = eh + (size_t)N_EMB * DIM;
    float*    esq     = (float*)(el + (size_t)N_EMB * DIM);
    int*      cand_idx= (int*)(esq + N_EMB);
    float*    partials= (float*)(cand_idx + (size_t)NCHUNK * N_VOX);

    esq_kernel    <<<dim3(N_EMB * 64 / 256), dim3(256), 0, stream>>>(cb, esq);
    cbprep_kernel <<<dim3(NTILE_TOT * 2 * 64 / 256), dim3(256), 0, stream>>>(cb, eh, el);
    scan_kernel   <<<dim3(512 / 4 * NCHUNK), dim3(256), 0, stream>>>(z, eh, el, esq, cand_idx);
    finalize_kernel<<<dim3(N_VOX / 256), dim3(256), 0, stream>>>(z, cb, esq, cand_idx, out, partials);
    loss_kernel   <<<1, 128, 0, stream>>>(partials, out);
}